// Round 2
// baseline (469.547 us; speedup 1.0000x reference)
//
#include <hip/hip_runtime.h>
#include <math.h>

#define LSEQ   350
#define DDIM   768
#define NPAIR  224
#define MROWS1 78400
#define NSLAB1 613      // fallback path
#define MAXSLAB 520     // ceil(224*297/128) worst-case compacted slabs

typedef short bf16x8 __attribute__((ext_vector_type(8)));
typedef float f32x4  __attribute__((ext_vector_type(4)));

typedef const unsigned int __attribute__((address_space(1)))* gas_ptr;
typedef unsigned int __attribute__((address_space(3)))* las_ptr;

__device__ __forceinline__ void gload_lds16(const void* g, void* l) {
  __builtin_amdgcn_global_load_lds((gas_ptr)g, (las_ptr)l, 16, 0, 0);
}

__device__ __forceinline__ unsigned short f2bf(float x) {
  unsigned int u = __float_as_uint(x);
  unsigned int r = (u + 0x7FFFu + ((u >> 16) & 1u)) >> 16;  // RNE
  return (unsigned short)r;
}

__device__ __forceinline__ float tanh_fast(float x) {
  float e = __expf(2.f * x);
  return 1.f - 2.f / (e + 1.f);
}

// ---------------- kernel: fused prep + conv ----------------
// blocks [0, 2688): X -> compacted Xbf (each block self-computes off[p])
// blocks [2688, 3840): W1/W2 -> Wt1/Wt2 transpose+bf16 (576 each)
// block 3840: exclusive prefix scan of (ss[p]-1) -> off[0..NPAIR]
// blocks (3840, 3840+402]: zero scores_c|sc|emb region (4 KiB per block)
// No inter-block dependencies: conv blocks overlap transpose/zero work.
#define PREP_CV 2688
#define PREP_WT 1152
#define PREP_ZB 402
#define PREP_SCAN (PREP_CV + PREP_WT)
__global__ __launch_bounds__(256) void k_prep(
    const float* __restrict__ X, const float* __restrict__ W1,
    const float* __restrict__ W2, unsigned short* __restrict__ Wt1,
    unsigned short* __restrict__ Wt2, const int* __restrict__ ssep,
    int* __restrict__ off, unsigned int* __restrict__ zreg,
    unsigned short* __restrict__ Xbf) {
  const int b = blockIdx.x;
  const int t = threadIdx.x;
  if (b < PREP_CV) {
    // ---- conv: pair p rows l=1..ss[p]-1 land at Xbf[off[p]+l-1] ----
    const int p = b / 12;
    const int rem = b - p * 12;
    const int nrow = ssep[p] - 1;
    const int r0 = (rem >> 2) * 128 + (rem & 3) * 32;
    if (r0 >= nrow) return;  // uniform
    // off[p] = sum_{i<p} (ssep[i]-1), masked block-reduce (L2-resident ints)
    __shared__ int sbuf[256];
    sbuf[t] = (t < NPAIR && t < p) ? (ssep[t] - 1) : 0;
    __syncthreads();
#pragma unroll
    for (int d = 128; d > 0; d >>= 1) {
      if (t < d) sbuf[t] += sbuf[t + d];
      __syncthreads();
    }
    const int o = sbuf[0];
    if (t < 192) {
      const int half = t / 96;        // 0/1: row parity
      const int tt = t - half * 96;   // 0..95: 8 floats each
      const int rmax = min(32, nrow - r0);
      const float* src = X + ((size_t)p * LSEQ + 1 + r0) * DDIM + tt * 8;
      unsigned short* dst = Xbf + (size_t)(o + r0) * DDIM + tt * 8;
#pragma unroll 4
      for (int rr = half; rr < rmax; rr += 2) {
        const float* s = src + (size_t)rr * DDIM;
        float4 x = *(const float4*)s;
        float4 y = *(const float4*)(s + 4);
        unsigned int ux = __float_as_uint(x.x) + 0x8000u;
        unsigned int uy = __float_as_uint(x.y) + 0x8000u;
        unsigned int uz = __float_as_uint(x.z) + 0x8000u;
        unsigned int uw = __float_as_uint(x.w) + 0x8000u;
        unsigned int vx = __float_as_uint(y.x) + 0x8000u;
        unsigned int vy = __float_as_uint(y.y) + 0x8000u;
        unsigned int vz = __float_as_uint(y.z) + 0x8000u;
        unsigned int vw = __float_as_uint(y.w) + 0x8000u;
        *(uint4*)(dst + (size_t)rr * DDIM) =
            make_uint4(__builtin_amdgcn_perm(uy, ux, 0x07060302u),
                       __builtin_amdgcn_perm(uw, uz, 0x07060302u),
                       __builtin_amdgcn_perm(vy, vx, 0x07060302u),
                       __builtin_amdgcn_perm(vw, vz, 0x07060302u));
      }
    }
  } else if (b < PREP_SCAN) {
    const int br = b - PREP_CV;
    const float* W = (br >= 576) ? W2 : W1;
    unsigned short* Wt = (br >= 576) ? Wt2 : Wt1;
    const int r = (br >= 576) ? br - 576 : br;
    const int bk = (r % 24) * 32, bn = (r / 24) * 32;
    __shared__ float tile[32][33];
    const int tx = t & 31, ty = t >> 5;
#pragma unroll
    for (int i = 0; i < 32; i += 8)
      tile[ty + i][tx] = W[(size_t)(bk + ty + i) * DDIM + bn + tx];
    __syncthreads();
#pragma unroll
    for (int i = 0; i < 32; i += 8)
      Wt[(size_t)(bn + ty + i) * DDIM + bk + tx] = f2bf(tile[tx][ty + i]);
  } else if (b == PREP_SCAN) {
    __shared__ int buf[256];
    int v = (t < NPAIR) ? (ssep[t] - 1) : 0;
    buf[t] = v;
    __syncthreads();
#pragma unroll
    for (int d = 1; d < 256; d <<= 1) {
      int add = (t >= d) ? buf[t - d] : 0;
      __syncthreads();
      buf[t] += add;
      __syncthreads();
    }
    if (t < NPAIR) off[t] = buf[t] - v;          // exclusive
    if (t == NPAIR - 1) off[NPAIR] = buf[t];     // total compacted rows
  } else {
    const int i = b - PREP_SCAN - 1;
    *((uint4*)zreg + (size_t)i * 256 + t) = make_uint4(0u, 0u, 0u, 0u);
  }
}

// ---------------- kernel: compacted bf16 GEMM + tanh-dot epilogue ----------------
// grid = 65*48. decode: g=b/48, r=b%48; slab=g*8+(r&7), nchunk=r>>3. The 6 nchunks
// of one slab run consecutively on the SAME XCD (round-robin %8) -> A-slab from L2.
// m97 structure, BK=64: half the barrier pairs of BK=32 (stage+drain dominates the
// 2-phase critical path per m233); LDS 32KB/block keeps 4 blocks/CU.
__global__ __launch_bounds__(256, 4) void k_gemm_c(
    const unsigned short* __restrict__ Xbf, const unsigned short* __restrict__ Wt,
    const float* __restrict__ bias, const float* __restrict__ vv,
    const int* __restrict__ off, float* __restrict__ scores_c) {
  const int Mtotal = off[NPAIR];
  const int b = blockIdx.x;
  const int g = b / 48, r = b - g * 48;
  const int slab = g * 8 + (r & 7);
  const int nchunk = r >> 3;
  if (slab * 128 >= Mtotal) return;  // uniform, before any barrier

  const size_t arow0 = (size_t)slab * 128;
  const int n0 = nchunk * 128;

  __shared__ unsigned short As[128 * 64];
  __shared__ unsigned short Bs[128 * 64];

  const int t = threadIdx.x;
  const int lane = t & 63, w = t >> 6;
  const int l15 = t & 15;
  const int quad = (t >> 4) & 3;
  const int wm = w >> 1, wn = w & 1;
  const int lrow8 = lane >> 3;       // DMA: row within 8-row segment
  const int lcol8 = (lane & 7) * 8;  // DMA: k offset (8 bf16 = 16 B)

  f32x4 acc[4][4];
#pragma unroll
  for (int mi = 0; mi < 4; ++mi)
#pragma unroll
    for (int ni = 0; ni < 4; ++ni)
#pragma unroll
      for (int q = 0; q < 4; ++q) acc[mi][ni][q] = 0.f;

  for (int k0 = 0; k0 < DDIM; k0 += 64) {
#pragma unroll
    for (int j = 0; j < 4; ++j) {
      int seg = w * 4 + j;  // 16 segments of 8 rows
      gload_lds16(Xbf + (arow0 + seg * 8 + lrow8) * DDIM + k0 + lcol8, As + seg * 512);
      gload_lds16(Wt + (size_t)(n0 + seg * 8 + lrow8) * DDIM + k0 + lcol8, Bs + seg * 512);
    }
    __syncthreads();

#pragma unroll
    for (int kk = 0; kk < 64; kk += 32) {
      bf16x8 a[4], bfr[4];
#pragma unroll
      for (int mi = 0; mi < 4; ++mi)
        a[mi] = *(const bf16x8*)&As[(wm * 64 + mi * 16 + l15) * 64 + kk + quad * 8];
#pragma unroll
      for (int ni = 0; ni < 4; ++ni)
        bfr[ni] = *(const bf16x8*)&Bs[(wn * 64 + ni * 16 + l15) * 64 + kk + quad * 8];
#pragma unroll
      for (int mi = 0; mi < 4; ++mi)
#pragma unroll
        for (int ni = 0; ni < 4; ++ni)
          acc[mi][ni] = __builtin_amdgcn_mfma_f32_16x16x32_bf16(a[mi], bfr[ni], acc[mi][ni], 0, 0, 0);
    }
    __syncthreads();
  }

  float vvv[4], bbv[4];
#pragma unroll
  for (int ni = 0; ni < 4; ++ni) {
    int n = n0 + wn * 64 + ni * 16 + l15;
    vvv[ni] = vv[n];
    bbv[ni] = bias[n];
  }
#pragma unroll
  for (int mi = 0; mi < 4; ++mi) {
#pragma unroll
    for (int reg = 0; reg < 4; ++reg) {
      float s = 0.f;
#pragma unroll
      for (int ni = 0; ni < 4; ++ni)
        s += tanh_fast(acc[mi][ni][reg] + bbv[ni]) * vvv[ni];
      s += __shfl_xor(s, 1);
      s += __shfl_xor(s, 2);
      s += __shfl_xor(s, 4);
      s += __shfl_xor(s, 8);
      if (l15 == mi * 4 + reg) {
        int row = (int)arow0 + wm * 64 + mi * 16 + quad * 4 + reg;
        if (row < Mtotal) atomicAdd(&scores_c[row], s);
      }
    }
  }
}

// ---------------- fallback big GEMM (R3): fused fp32->bf16 staging ----------------
__global__ __launch_bounds__(256, 2) void k_gemm_score(
    const float* __restrict__ X, const unsigned short* __restrict__ Wt,
    const float* __restrict__ bias, const float* __restrict__ vv,
    float* __restrict__ outs, int Mrows, int swz) {
  int slab, nchunk;
  if (swz) {
    int b = blockIdx.x;
    int g = b / 48, r = b - g * 48;
    slab = g * 8 + (r & 7);
    nchunk = r >> 3;
    if (slab >= NSLAB1) return;
  } else {
    slab = blockIdx.y;
    nchunk = blockIdx.x;
  }
  const int row0 = slab * 128;
  const int n0 = nchunk * 128;

  __shared__ unsigned short As[128][40];
  __shared__ unsigned short Bs[128][40];

  const int t = threadIdx.x;
  const int l15 = t & 15;
  const int quad = (t >> 4) & 3;
  const int w = t >> 6;
  const int wm = w >> 1, wn = w & 1;
  const int ar = t >> 3;
  const int ac = (t & 7) * 4;
  const int br = t >> 2;
  const int bc = (t & 3) * 8;

  f32x4 acc[4][4];
#pragma unroll
  for (int mi = 0; mi < 4; ++mi)
#pragma unroll
    for (int ni = 0; ni < 4; ++ni)
#pragma unroll
      for (int q = 0; q < 4; ++q) acc[mi][ni][q] = 0.f;

  for (int k0 = 0; k0 < DDIM; k0 += 32) {
#pragma unroll
    for (int pass = 0; pass < 4; ++pass) {
      int rr = ar + pass * 32;
      int row = row0 + rr;
      float4 x = make_float4(0.f, 0.f, 0.f, 0.f);
      if (row < Mrows) x = *(const float4*)(X + (size_t)row * DDIM + k0 + ac);
      unsigned int ux = __float_as_uint(x.x) + 0x8000u;
      unsigned int uy = __float_as_uint(x.y) + 0x8000u;
      unsigned int uz = __float_as_uint(x.z) + 0x8000u;
      unsigned int uw = __float_as_uint(x.w) + 0x8000u;
      *(uint2*)&As[rr][ac] = make_uint2(__builtin_amdgcn_perm(uy, ux, 0x07060302u),
                                        __builtin_amdgcn_perm(uw, uz, 0x07060302u));
    }
#pragma unroll
    for (int pp = 0; pp < 2; ++pp) {
      int rr = br + pp * 64;
      *(uint4*)&Bs[rr][bc] = *(const uint4*)(Wt + (size_t)(n0 + rr) * DDIM + k0 + bc);
    }
    __syncthreads();

    bf16x8 a[4], bfr[4];
#pragma unroll
    for (int mi = 0; mi < 4; ++mi)
      a[mi] = *(const bf16x8*)&As[wm * 64 + mi * 16 + l15][quad * 8];
#pragma unroll
    for (int ni = 0; ni < 4; ++ni)
      bfr[ni] = *(const bf16x8*)&Bs[wn * 64 + ni * 16 + l15][quad * 8];
#pragma unroll
    for (int mi = 0; mi < 4; ++mi)
#pragma unroll
      for (int ni = 0; ni < 4; ++ni)
        acc[mi][ni] = __builtin_amdgcn_mfma_f32_16x16x32_bf16(a[mi], bfr[ni], acc[mi][ni], 0, 0, 0);
    __syncthreads();
  }

  float vvv[4], bbv[4];
#pragma unroll
  for (int ni = 0; ni < 4; ++ni) {
    int n = n0 + wn * 64 + ni * 16 + l15;
    vvv[ni] = vv[n];
    bbv[ni] = bias[n];
  }
#pragma unroll
  for (int mi = 0; mi < 4; ++mi) {
#pragma unroll
    for (int reg = 0; reg < 4; ++reg) {
      float s = 0.f;
#pragma unroll
      for (int ni = 0; ni < 4; ++ni)
        s += tanh_fast(acc[mi][ni][reg] + bbv[ni]) * vvv[ni];
      s += __shfl_xor(s, 1);
      s += __shfl_xor(s, 2);
      s += __shfl_xor(s, 4);
      s += __shfl_xor(s, 8);
      if (l15 == mi * 4 + reg) {
        int row = row0 + wm * 64 + mi * 16 + quad * 4 + reg;
        if (row < Mrows) atomicAdd(&outs[row], s);
      }
    }
  }
}

// ---------------- block reduce helper (256 threads / 4 waves) ----------------
__device__ __forceinline__ float block_reduce(float v, bool is_max, float* redbuf) {
#pragma unroll
  for (int off = 1; off < 64; off <<= 1) {
    float o = __shfl_xor(v, off);
    v = is_max ? fmaxf(v, o) : (v + o);
  }
  int wv = threadIdx.x >> 6;
  if ((threadIdx.x & 63) == 0) redbuf[wv] = v;
  __syncthreads();
  float r = is_max ? fmaxf(fmaxf(redbuf[0], redbuf[1]), fmaxf(redbuf[2], redbuf[3]))
                   : (redbuf[0] + redbuf[1] + redbuf[2] + redbuf[3]);
  __syncthreads();
  return r;
}

// ---------------- kernel: softmax + pooling ----------------
// grid (NPAIR, 4): block c pools rows [1+c*nch, min(ss, 1+(c+1)*nch)).
// Softmax recomputed redundantly per block (cheap, bit-identical); partial
// pooled sums atomicAdd into zero-initialized emb.
__global__ __launch_bounds__(256) void k_pool3(
    const unsigned short* __restrict__ Xbf, const float* __restrict__ X,
    const float* __restrict__ scores_c, const int* __restrict__ fsep,
    const int* __restrict__ ssep, const int* __restrict__ off,
    float* __restrict__ emb, float* __restrict__ out) {
  const int p = blockIdx.x, c = blockIdx.y, t = threadIdx.x;
  const int fs = fsep[p], ss = ssep[p];
  const int o = off[p];
  __shared__ float sw1[LSEQ], sw2[LSEQ];
  __shared__ float redbuf[4];

  float m1p = -INFINITY, m2p = -INFINITY;
  for (int l = t; l < LSEQ; l += 256) {
    float s = (l >= 1 && l < ss) ? scores_c[o + l - 1] : 0.f;
    float s1 = (l >= 1 && l < fs) ? s : -INFINITY;
    float s2 = (l > fs && l < ss) ? s : -INFINITY;
    sw1[l] = s1; sw2[l] = s2;
    m1p = fmaxf(m1p, s1); m2p = fmaxf(m2p, s2);
  }
  __syncthreads();
  float m1 = block_reduce(m1p, true, redbuf);
  float m2 = block_reduce(m2p, true, redbuf);
  float d1p = 0.f, d2p = 0.f;
  for (int l = t; l < LSEQ; l += 256) {
    float e1v = __expf(sw1[l] - m1);
    float e2v = __expf(sw2[l] - m2);
    sw1[l] = e1v; sw2[l] = e2v;
    d1p += e1v; d2p += e2v;
  }
  __syncthreads();
  float inv1 = 1.f / block_reduce(d1p, false, redbuf);
  float inv2 = 1.f / block_reduce(d2p, false, redbuf);

  // all barriers done -- divergent tail is safe
  if (t < 192) {
    if (c == 0) {
      // pair_embeddings = all_output[:, 0, :] (exact fp32 copy)
      *(float4*)(out + (size_t)p * DDIM + t * 4) =
          *(const float4*)(X + (size_t)p * LSEQ * DDIM + t * 4);
    }

    const int nch = (ss + 2) >> 2;      // ceil((ss-1)/4)
    const int lo = 1 + c * nch;
    const int hi = min(ss, lo + nch);

    float A1[4] = {0.f, 0.f, 0.f, 0.f}, A2[4] = {0.f, 0.f, 0.f, 0.f};
    const unsigned short* xb = Xbf + (size_t)o * DDIM + t * 4;
#pragma unroll 4
    for (int l = lo; l < hi; ++l) {
      float wa = sw1[l] * inv1, wb = sw2[l] * inv2;
      uint2 xv = *(const uint2*)(xb + (size_t)(l - 1) * DDIM);
      float x0 = __uint_as_float((xv.x & 0xFFFFu) << 16);
      float x1 = __uint_as_float(xv.x & 0xFFFF0000u);
      float x2 = __uint_as_float((xv.y & 0xFFFFu) << 16);
      float x3 = __uint_as_float(xv.y & 0xFFFF0000u);
      A1[0] += wa * x0; A1[1] += wa * x1; A1[2] += wa * x2; A1[3] += wa * x3;
      A2[0] += wb * x0; A2[1] += wb * x1; A2[2] += wb * x2; A2[3] += wb * x3;
    }
    float* e1 = emb + (size_t)(2 * p) * DDIM + t * 4;
    float* e2 = emb + (size_t)(2 * p + 1) * DDIM + t * 4;
    atomicAdd(&e1[0], A1[0]); atomicAdd(&e1[1], A1[1]);
    atomicAdd(&e1[2], A1[2]); atomicAdd(&e1[3], A1[3]);
    atomicAdd(&e2[0], A2[0]); atomicAdd(&e2[1], A2[1]);
    atomicAdd(&e2[2], A2[2]); atomicAdd(&e2[3], A2[3]);
  }
}

// ---------------- fallback kernels (R3 path) ----------------
__global__ __launch_bounds__(256) void k_w1t(const float* __restrict__ W,
                                             unsigned short* __restrict__ Wt) {
  __shared__ float tile[32][33];
  int bk = blockIdx.x * 32, bn = blockIdx.y * 32;
  int tx = threadIdx.x & 31, ty = threadIdx.x >> 5;
#pragma unroll
  for (int i = 0; i < 32; i += 8)
    tile[ty + i][tx] = W[(size_t)(bk + ty + i) * DDIM + bn + tx];
  __syncthreads();
#pragma unroll
  for (int i = 0; i < 32; i += 8)
    Wt[(size_t)(bn + ty + i) * DDIM + bk + tx] = f2bf(tile[tx][ty + i]);
}

__global__ __launch_bounds__(256) void k_pool(
    const float* __restrict__ X, const float* __restrict__ scores,
    const int* __restrict__ fsep, const int* __restrict__ ssep,
    float* __restrict__ emb, float* __restrict__ out) {
  const int p = blockIdx.x;
  const int c = blockIdx.y;
  const int t = threadIdx.x;
  const int fs = fsep[p], ss = ssep[p];
  __shared__ float sw1[LSEQ], sw2[LSEQ];
  __shared__ float redbuf[4];

  float m1p = -INFINITY, m2p = -INFINITY;
  for (int l = t; l < LSEQ; l += 256) {
    float s = scores[p * LSEQ + l];
    float s1 = (l >= 1 && l < fs) ? s : -INFINITY;
    float s2 = (l > fs && l < ss) ? s : -INFINITY;
    sw1[l] = s1; sw2[l] = s2;
    m1p = fmaxf(m1p, s1); m2p = fmaxf(m2p, s2);
  }
  __syncthreads();
  float m1 = block_reduce(m1p, true, redbuf);
  float m2 = block_reduce(m2p, true, redbuf);
  float d1p = 0.f, d2p = 0.f;
  for (int l = t; l < LSEQ; l += 256) {
    float e1v = __expf(sw1[l] - m1);
    float e2v = __expf(sw2[l] - m2);
    sw1[l] = e1v; sw2[l] = e2v;
    d1p += e1v; d2p += e2v;
  }
  __syncthreads();
  float inv1 = 1.f / block_reduce(d1p, false, redbuf);
  float inv2 = 1.f / block_reduce(d2p, false, redbuf);
  const float* base = X + (size_t)p * LSEQ * DDIM;
  if (c == 0) {
    float* po = out + (size_t)p * DDIM;
    po[t] = base[t]; po[t + 256] = base[t + 256]; po[t + 512] = base[t + 512];
  }
  if (t < 192) {
    float4 A1 = make_float4(0.f, 0.f, 0.f, 0.f);
    float4 A2 = make_float4(0.f, 0.f, 0.f, 0.f);
    for (int l = 1 + c; l < ss; l += 8) {
      float wa = sw1[l] * inv1, wb = sw2[l] * inv2;
      float4 x = *(const float4*)(base + (size_t)l * DDIM + 4 * t);
      A1.x += wa * x.x; A1.y += wa * x.y; A1.z += wa * x.z; A1.w += wa * x.w;
      A2.x += wb * x.x; A2.y += wb * x.y; A2.z += wb * x.z; A2.w += wb * x.w;
    }
    float* e1 = emb + (size_t)(2 * p) * DDIM + 4 * t;
    float* e2 = emb + (size_t)(2 * p + 1) * DDIM + 4 * t;
    atomicAdd(&e1[0], A1.x); atomicAdd(&e1[1], A1.y);
    atomicAdd(&e1[2], A1.z); atomicAdd(&e1[3], A1.w);
    atomicAdd(&e2[0], A2.x); atomicAdd(&e2[1], A2.y);
    atomicAdd(&e2[2], A2.z); atomicAdd(&e2[3], A2.w);
  }
}

// ---------------- kernel: segment softmax + weighted sum ----------------
__global__ __launch_bounds__(256) void k_segout(
    const float* __restrict__ emb, const float* __restrict__ sc,
    float* __restrict__ out2) {
  const int g = blockIdx.x;  // 0..31
  const int z = g >> 3, j = g & 7;
  const int t = threadIdx.x;
  int ee[14];
#pragma unroll
  for (int i = 0; i < 7; ++i) ee[i] = 2 * (z * 56 + j * 7 + i);
#pragma unroll
  for (int i = 0; i < 7; ++i) {
    int j2 = i + (i >= j ? 1 : 0);
    int kk = j - (j > j2 ? 1 : 0);
    ee[7 + i] = 2 * (z * 56 + j2 * 7 + kk) + 1;
  }
  float sv[14];
  float m = -INFINITY;
#pragma unroll
  for (int i = 0; i < 14; ++i) { sv[i] = sc[ee[i]]; m = fmaxf(m, sv[i]); }
  float den = 0.f;
#pragma unroll
  for (int i = 0; i < 14; ++i) { sv[i] = __expf(sv[i] - m); den += sv[i]; }
  float inv = 1.f / den;
  float a0 = 0.f, a1 = 0.f, a2 = 0.f;
#pragma unroll
  for (int i = 0; i < 14; ++i) {
    float wgt = sv[i] * inv;
    const float* er = emb + (size_t)ee[i] * DDIM;
    a0 += wgt * er[t]; a1 += wgt * er[t + 256]; a2 += wgt * er[t + 512];
  }
  out2[(size_t)g * DDIM + t] = a0;
  out2[(size_t)g * DDIM + t + 256] = a1;
  out2[(size_t)g * DDIM + t + 512] = a2;
}

// ---------------- launcher ----------------
extern "C" void kernel_launch(void* const* d_in, const int* in_sizes, int n_in,
                              void* d_out, int out_size, void* d_ws, size_t ws_size,
                              hipStream_t stream) {
  const float* X  = (const float*)d_in[0];
  const int* fs   = (const int*)d_in[1];
  const int* ss   = (const int*)d_in[2];
  const float* W1 = (const float*)d_in[3];
  const float* b1 = (const float*)d_in[4];
  const float* v1 = (const float*)d_in[5];
  const float* W2 = (const float*)d_in[7];
  const float* b2 = (const float*)d_in[8];
  const float* v2 = (const float*)d_in[9];
  float* out = (float*)d_out;

  char* ws = (char*)d_ws;
  // fast-path layout (256-B aligned)
  const size_t XBF_ROWS = (size_t)MAXSLAB * 128 + 128;           // 66,688 rows (128 pad)
  const size_t OFF_OFF  = XBF_ROWS * DDIM * 2;                   // 102,432,768
  const size_t OFF_WT1  = OFF_OFF + 1024;
  const size_t OFF_WT2  = OFF_WT1 + 1179648;
  const size_t OFF_SCC  = OFF_WT2 + 1179648;                     // scores_c: 66,688*4 = 266,752
  const size_t OFF_SC2  = OFF_SCC + 266752;                      // sc: 448*4 -> pad
  const size_t OFF_EMB  = OFF_SCC + 269312;                      // emb (zeroed, atomicAdd target)
  const size_t ZBYTES   = (size_t)PREP_ZB * 4096;                // 1,646,592 zeroed (scc+sc+emb)
  const size_t NEED     = OFF_SCC + ZBYTES + 256;                // ~106.4 MB

  if (ws_size >= NEED) {
    unsigned short* Xbf = (unsigned short*)ws;
    int*   off     = (int*)(ws + OFF_OFF);
    unsigned short* Wt1 = (unsigned short*)(ws + OFF_WT1);
    unsigned short* Wt2 = (unsigned short*)(ws + OFF_WT2);
    float* scores_c = (float*)(ws + OFF_SCC);
    float* sc       = (float*)(ws + OFF_SC2);
    float* emb      = (float*)(ws + OFF_EMB);

    k_prep<<<PREP_SCAN + 1 + PREP_ZB, 256, 0, stream>>>(
        X, W1, W2, Wt1, Wt2, ss, off, (unsigned int*)scores_c, Xbf);
    k_gemm_c<<<65 * 48, 256, 0, stream>>>(Xbf, Wt1, b1, v1, off, scores_c);
    k_pool3<<<dim3(NPAIR, 4), 256, 0, stream>>>(Xbf, X, scores_c, fs, ss, off, emb, out);
    k_gemm_score<<<dim3(6, 4), 256, 0, stream>>>(emb, Wt2, b2, v2, sc, 448, 0);
    k_segout<<<32, 256, 0, stream>>>(emb, sc, out + (size_t)NPAIR * DDIM);
  } else {
    // fallback (R3 path, ~2.9 MB ws)
    unsigned short* Wt = (unsigned short*)ws;
    float* scores = (float*)(ws + 1179648);
    float* emb    = (float*)(ws + 1493248);
    float* sc     = scores;

    k_w1t<<<dim3(24, 24), 256, 0, stream>>>(W1, Wt);
    hipMemsetAsync(scores, 0, MROWS1 * sizeof(float), stream);
    hipMemsetAsync(emb, 0, 448 * DDIM * sizeof(float), stream);
    k_gemm_score<<<77 * 48, 256, 0, stream>>>(X, Wt, b1, v1, scores, MROWS1, 1);
    k_pool<<<dim3(NPAIR, 8), 256, 0, stream>>>(X, scores, fs, ss, emb, out);
    k_w1t<<<dim3(24, 24), 256, 0, stream>>>(W2, Wt);
    hipMemsetAsync(sc, 0, 448 * sizeof(float), stream);
    k_gemm_score<<<dim3(6, 4), 256, 0, stream>>>(emb, Wt, b2, v2, sc, 448, 0);
    k_segout<<<32, 256, 0, stream>>>(emb, sc, out + (size_t)NPAIR * DDIM);
  }
}

// Round 5
// 467.881 us; speedup vs baseline: 1.0036x; 1.0036x over previous
//
#include <hip/hip_runtime.h>
#include <math.h>

#define LSEQ   350
#define DDIM   768
#define NPAIR  224
#define MROWS1 78400
#define NSLAB1 613      // fallback path
#define MAXSLAB 520     // ceil(224*297/128) worst-case compacted slabs
#define SPROWS 66688    // scores_part row capacity (MAXSLAB*128+128)

typedef short bf16x8 __attribute__((ext_vector_type(8)));
typedef float f32x4  __attribute__((ext_vector_type(4)));

typedef const unsigned int __attribute__((address_space(1)))* gas_ptr;
typedef unsigned int __attribute__((address_space(3)))* las_ptr;

__device__ __forceinline__ void gload_lds16(const void* g, void* l) {
  __builtin_amdgcn_global_load_lds((gas_ptr)g, (las_ptr)l, 16, 0, 0);
}

__device__ __forceinline__ unsigned short f2bf(float x) {
  unsigned int u = __float_as_uint(x);
  unsigned int r = (u + 0x7FFFu + ((u >> 16) & 1u)) >> 16;  // RNE
  return (unsigned short)r;
}

__device__ __forceinline__ float tanh_fast(float x) {
  float e = __expf(2.f * x);
  return 1.f - 2.f / (e + 1.f);
}

// ---------------- kernel: fused prep + conv ----------------
// blocks [0, 2688): X -> compacted Xbf (each block self-computes off[p] via
//   barrier-free per-wave shuffle reduce)
// blocks [2688, 3840): W1/W2 -> Wt1/Wt2 transpose+bf16 (576 each)
// block 3840: exclusive prefix scan of (ss[p]-1) -> off[0..NPAIR]
// blocks (3840, 3840+337]: zero sc|emb region (4 KiB per block)
#define PREP_CV 2688
#define PREP_WT 1152
#define PREP_ZB 337
#define PREP_SCAN (PREP_CV + PREP_WT)
__global__ __launch_bounds__(256) void k_prep(
    const float* __restrict__ X, const float* __restrict__ W1,
    const float* __restrict__ W2, unsigned short* __restrict__ Wt1,
    unsigned short* __restrict__ Wt2, const int* __restrict__ ssep,
    int* __restrict__ off, unsigned int* __restrict__ zreg,
    unsigned short* __restrict__ Xbf) {
  const int b = blockIdx.x;
  const int t = threadIdx.x;
  if (b < PREP_CV) {
    // ---- conv: pair p rows l=1..ss[p]-1 land at Xbf[off[p]+l-1] ----
    const int p = b / 12;
    const int rem = b - p * 12;
    const int nrow = ssep[p] - 1;
    const int r0 = (rem >> 2) * 128 + (rem & 3) * 32;
    if (r0 >= nrow) return;  // uniform
    // off[p] = sum_{i<p} (ssep[i]-1): per-wave shuffle reduce, no barriers
    const int lane = t & 63;
    int accv = 0;
    for (int i = lane; i < NPAIR; i += 64) accv += (i < p) ? (ssep[i] - 1) : 0;
#pragma unroll
    for (int d = 1; d < 64; d <<= 1) accv += __shfl_xor(accv, d);
    const int o = accv;
    if (t < 192) {
      const int half = t / 96;        // 0/1: row parity
      const int tt = t - half * 96;   // 0..95: 8 floats each
      const int rmax = min(32, nrow - r0);
      const float* src = X + ((size_t)p * LSEQ + 1 + r0) * DDIM + tt * 8;
      unsigned short* dst = Xbf + (size_t)(o + r0) * DDIM + tt * 8;
#pragma unroll 4
      for (int rr = half; rr < rmax; rr += 2) {
        const float* s = src + (size_t)rr * DDIM;
        float4 x = *(const float4*)s;
        float4 y = *(const float4*)(s + 4);
        unsigned int ux = __float_as_uint(x.x) + 0x8000u;
        unsigned int uy = __float_as_uint(x.y) + 0x8000u;
        unsigned int uz = __float_as_uint(x.z) + 0x8000u;
        unsigned int uw = __float_as_uint(x.w) + 0x8000u;
        unsigned int vx = __float_as_uint(y.x) + 0x8000u;
        unsigned int vy = __float_as_uint(y.y) + 0x8000u;
        unsigned int vz = __float_as_uint(y.z) + 0x8000u;
        unsigned int vw = __float_as_uint(y.w) + 0x8000u;
        *(uint4*)(dst + (size_t)rr * DDIM) =
            make_uint4(__builtin_amdgcn_perm(uy, ux, 0x07060302u),
                       __builtin_amdgcn_perm(uw, uz, 0x07060302u),
                       __builtin_amdgcn_perm(vy, vx, 0x07060302u),
                       __builtin_amdgcn_perm(vw, vz, 0x07060302u));
      }
    }
  } else if (b < PREP_SCAN) {
    const int br = b - PREP_CV;
    const float* W = (br >= 576) ? W2 : W1;
    unsigned short* Wt = (br >= 576) ? Wt2 : Wt1;
    const int r = (br >= 576) ? br - 576 : br;
    const int bk = (r % 24) * 32, bn = (r / 24) * 32;
    __shared__ float tile[32][33];
    const int tx = t & 31, ty = t >> 5;
#pragma unroll
    for (int i = 0; i < 32; i += 8)
      tile[ty + i][tx] = W[(size_t)(bk + ty + i) * DDIM + bn + tx];
    __syncthreads();
#pragma unroll
    for (int i = 0; i < 32; i += 8)
      Wt[(size_t)(bn + ty + i) * DDIM + bk + tx] = f2bf(tile[tx][ty + i]);
  } else if (b == PREP_SCAN) {
    __shared__ int buf[256];
    int v = (t < NPAIR) ? (ssep[t] - 1) : 0;
    buf[t] = v;
    __syncthreads();
#pragma unroll
    for (int d = 1; d < 256; d <<= 1) {
      int add = (t >= d) ? buf[t - d] : 0;
      __syncthreads();
      buf[t] += add;
      __syncthreads();
    }
    if (t < NPAIR) off[t] = buf[t] - v;          // exclusive
    if (t == NPAIR - 1) off[NPAIR] = buf[t];     // total compacted rows
  } else {
    const int i = b - PREP_SCAN - 1;
    *((uint4*)zreg + (size_t)i * 256 + t) = make_uint4(0u, 0u, 0u, 0u);
  }
}

// ---------------- kernel: compacted bf16 GEMM + tanh-dot epilogue ----------------
// grid = 65*48. decode: g=b/48, r=b%48; slab=g*8+(r&7), nchunk=r>>3. The 6 nchunks
// of one slab run consecutively on the SAME XCD (round-robin %8) -> A-slab from L2.
// T3-minimum double-buffer: STAGE(t+1) issued before compute(t); one barrier per
// K-step (compiler's pre-barrier vmcnt(0) drains a latency-hidden load).
// LDS slot-swizzle (both-sides, rule #21): global src col XOR'd by (row>>1)&3 on
// 16B slots, ds_read applies the same XOR -> quarter-wave banks 8-way -> 2-way.
// Epilogue: plain stores to scores_part[nchunk*2+wn][row] (no atomics, no zeroing).
__global__ __launch_bounds__(256, 4) void k_gemm_c(
    const unsigned short* __restrict__ Xbf, const unsigned short* __restrict__ Wt,
    const float* __restrict__ bias, const float* __restrict__ vv,
    const int* __restrict__ off, float* __restrict__ scores_part) {
  const int Mtotal = off[NPAIR];
  const int b = blockIdx.x;
  const int g = b / 48, r = b - g * 48;
  const int slab = g * 8 + (r & 7);
  const int nchunk = r >> 3;
  if (slab * 128 >= Mtotal) return;  // uniform, before any barrier

  const size_t arow0 = (size_t)slab * 128;
  const int n0 = nchunk * 128;

  __shared__ unsigned short As[2][128 * 32];
  __shared__ unsigned short Bs[2][128 * 32];

  const int t = threadIdx.x;
  const int lane = t & 63, w = t >> 6;
  const int l15 = t & 15;
  const int quad = (t >> 4) & 3;
  const int wm = w >> 1, wn = w & 1;
  const int lrow = lane >> 2;                              // row within 16-row segment
  const int scol = ((lane & 3) ^ ((lane >> 3) & 3)) * 8;   // pre-swizzled k offset

  f32x4 acc[4][4];
#pragma unroll
  for (int mi = 0; mi < 4; ++mi)
#pragma unroll
    for (int ni = 0; ni < 4; ++ni)
#pragma unroll
      for (int q = 0; q < 4; ++q) acc[mi][ni][q] = 0.f;

  auto stage = [&](int bi, int kk0) {
#pragma unroll
    for (int j = 0; j < 2; ++j) {
      int seg = w * 2 + j;
      gload_lds16(Xbf + (arow0 + seg * 16 + lrow) * DDIM + kk0 + scol, &As[bi][seg * 512]);
      gload_lds16(Wt + (size_t)(n0 + seg * 16 + lrow) * DDIM + kk0 + scol, &Bs[bi][seg * 512]);
    }
  };

  stage(0, 0);
  __syncthreads();

  const int qs = (quad ^ ((l15 >> 1) & 3)) * 8;  // swizzled read slot
  int cur = 0;
#pragma unroll 1
  for (int step = 0; step < DDIM / 32; ++step) {
    if (step < DDIM / 32 - 1) stage(cur ^ 1, (step + 1) * 32);

    bf16x8 a[4], bfr[4];
#pragma unroll
    for (int mi = 0; mi < 4; ++mi)
      a[mi] = *(const bf16x8*)&As[cur][(wm * 64 + mi * 16 + l15) * 32 + qs];
#pragma unroll
    for (int ni = 0; ni < 4; ++ni)
      bfr[ni] = *(const bf16x8*)&Bs[cur][(wn * 64 + ni * 16 + l15) * 32 + qs];
#pragma unroll
    for (int mi = 0; mi < 4; ++mi)
#pragma unroll
      for (int ni = 0; ni < 4; ++ni)
        acc[mi][ni] = __builtin_amdgcn_mfma_f32_16x16x32_bf16(a[mi], bfr[ni], acc[mi][ni], 0, 0, 0);
    __syncthreads();
    cur ^= 1;
  }

  float vvv[4], bbv[4];
#pragma unroll
  for (int ni = 0; ni < 4; ++ni) {
    int n = n0 + wn * 64 + ni * 16 + l15;
    vvv[ni] = vv[n];
    bbv[ni] = bias[n];
  }
  float* spdst = scores_part + (size_t)(nchunk * 2 + wn) * SPROWS;
#pragma unroll
  for (int mi = 0; mi < 4; ++mi) {
#pragma unroll
    for (int reg = 0; reg < 4; ++reg) {
      float s = 0.f;
#pragma unroll
      for (int ni = 0; ni < 4; ++ni)
        s += tanh_fast(acc[mi][ni][reg] + bbv[ni]) * vvv[ni];
      s += __shfl_xor(s, 1);
      s += __shfl_xor(s, 2);
      s += __shfl_xor(s, 4);
      s += __shfl_xor(s, 8);
      if (l15 == mi * 4 + reg) {
        int row = (int)arow0 + wm * 64 + mi * 16 + quad * 4 + reg;
        if (row < Mtotal) spdst[row] = s;
      }
    }
  }
}

// ---------------- fallback big GEMM (R3): fused fp32->bf16 staging ----------------
__global__ __launch_bounds__(256, 2) void k_gemm_score(
    const float* __restrict__ X, const unsigned short* __restrict__ Wt,
    const float* __restrict__ bias, const float* __restrict__ vv,
    float* __restrict__ outs, int Mrows, int swz) {
  int slab, nchunk;
  if (swz) {
    int b = blockIdx.x;
    int g = b / 48, r = b - g * 48;
    slab = g * 8 + (r & 7);
    nchunk = r >> 3;
    if (slab >= NSLAB1) return;
  } else {
    slab = blockIdx.y;
    nchunk = blockIdx.x;
  }
  const int row0 = slab * 128;
  const int n0 = nchunk * 128;

  __shared__ unsigned short As[128][40];
  __shared__ unsigned short Bs[128][40];

  const int t = threadIdx.x;
  const int l15 = t & 15;
  const int quad = (t >> 4) & 3;
  const int w = t >> 6;
  const int wm = w >> 1, wn = w & 1;
  const int ar = t >> 3;
  const int ac = (t & 7) * 4;
  const int br = t >> 2;
  const int bc = (t & 3) * 8;

  f32x4 acc[4][4];
#pragma unroll
  for (int mi = 0; mi < 4; ++mi)
#pragma unroll
    for (int ni = 0; ni < 4; ++ni)
#pragma unroll
      for (int q = 0; q < 4; ++q) acc[mi][ni][q] = 0.f;

  for (int k0 = 0; k0 < DDIM; k0 += 32) {
#pragma unroll
    for (int pass = 0; pass < 4; ++pass) {
      int rr = ar + pass * 32;
      int row = row0 + rr;
      float4 x = make_float4(0.f, 0.f, 0.f, 0.f);
      if (row < Mrows) x = *(const float4*)(X + (size_t)row * DDIM + k0 + ac);
      unsigned int ux = __float_as_uint(x.x) + 0x8000u;
      unsigned int uy = __float_as_uint(x.y) + 0x8000u;
      unsigned int uz = __float_as_uint(x.z) + 0x8000u;
      unsigned int uw = __float_as_uint(x.w) + 0x8000u;
      *(uint2*)&As[rr][ac] = make_uint2(__builtin_amdgcn_perm(uy, ux, 0x07060302u),
                                        __builtin_amdgcn_perm(uw, uz, 0x07060302u));
    }
#pragma unroll
    for (int pp = 0; pp < 2; ++pp) {
      int rr = br + pp * 64;
      *(uint4*)&Bs[rr][bc] = *(const uint4*)(Wt + (size_t)(n0 + rr) * DDIM + k0 + bc);
    }
    __syncthreads();

    bf16x8 a[4], bfr[4];
#pragma unroll
    for (int mi = 0; mi < 4; ++mi)
      a[mi] = *(const bf16x8*)&As[wm * 64 + mi * 16 + l15][quad * 8];
#pragma unroll
    for (int ni = 0; ni < 4; ++ni)
      bfr[ni] = *(const bf16x8*)&Bs[wn * 64 + ni * 16 + l15][quad * 8];
#pragma unroll
    for (int mi = 0; mi < 4; ++mi)
#pragma unroll
      for (int ni = 0; ni < 4; ++ni)
        acc[mi][ni] = __builtin_amdgcn_mfma_f32_16x16x32_bf16(a[mi], bfr[ni], acc[mi][ni], 0, 0, 0);
    __syncthreads();
  }

  float vvv[4], bbv[4];
#pragma unroll
  for (int ni = 0; ni < 4; ++ni) {
    int n = n0 + wn * 64 + ni * 16 + l15;
    vvv[ni] = vv[n];
    bbv[ni] = bias[n];
  }
#pragma unroll
  for (int mi = 0; mi < 4; ++mi) {
#pragma unroll
    for (int reg = 0; reg < 4; ++reg) {
      float s = 0.f;
#pragma unroll
      for (int ni = 0; ni < 4; ++ni)
        s += tanh_fast(acc[mi][ni][reg] + bbv[ni]) * vvv[ni];
      s += __shfl_xor(s, 1);
      s += __shfl_xor(s, 2);
      s += __shfl_xor(s, 4);
      s += __shfl_xor(s, 8);
      if (l15 == mi * 4 + reg) {
        int row = row0 + wm * 64 + mi * 16 + quad * 4 + reg;
        if (row < Mrows) atomicAdd(&outs[row], s);
      }
    }
  }
}

// ---------------- block reduce helper (256 threads / 4 waves) ----------------
__device__ __forceinline__ float block_reduce(float v, bool is_max, float* redbuf) {
#pragma unroll
  for (int off = 1; off < 64; off <<= 1) {
    float o = __shfl_xor(v, off);
    v = is_max ? fmaxf(v, o) : (v + o);
  }
  int wv = threadIdx.x >> 6;
  if ((threadIdx.x & 63) == 0) redbuf[wv] = v;
  __syncthreads();
  float r = is_max ? fmaxf(fmaxf(redbuf[0], redbuf[1]), fmaxf(redbuf[2], redbuf[3]))
                   : (redbuf[0] + redbuf[1] + redbuf[2] + redbuf[3]);
  __syncthreads();
  return r;
}

// ---------------- kernel: softmax + pooling ----------------
// grid (NPAIR, 4): block c pools rows [1+c*nch, min(ss, 1+(c+1)*nch)).
// Scores come as 12 partials (scores_part[12][SPROWS]), summed here (L2-resident).
__global__ __launch_bounds__(256) void k_pool3(
    const unsigned short* __restrict__ Xbf, const float* __restrict__ X,
    const float* __restrict__ sp, const int* __restrict__ fsep,
    const int* __restrict__ ssep, const int* __restrict__ off,
    float* __restrict__ emb, float* __restrict__ out) {
  const int p = blockIdx.x, c = blockIdx.y, t = threadIdx.x;
  const int fs = fsep[p], ss = ssep[p];
  const int o = off[p];
  __shared__ float sw1[LSEQ], sw2[LSEQ];
  __shared__ float redbuf[4];

  float m1p = -INFINITY, m2p = -INFINITY;
  for (int l = t; l < LSEQ; l += 256) {
    float s = 0.f;
    if (l >= 1 && l < ss) {
      const int idx = o + l - 1;
#pragma unroll
      for (int c6 = 0; c6 < 12; ++c6) s += sp[(size_t)c6 * SPROWS + idx];
    }
    float s1 = (l >= 1 && l < fs) ? s : -INFINITY;
    float s2 = (l > fs && l < ss) ? s : -INFINITY;
    sw1[l] = s1; sw2[l] = s2;
    m1p = fmaxf(m1p, s1); m2p = fmaxf(m2p, s2);
  }
  __syncthreads();
  float m1 = block_reduce(m1p, true, redbuf);
  float m2 = block_reduce(m2p, true, redbuf);
  float d1p = 0.f, d2p = 0.f;
  for (int l = t; l < LSEQ; l += 256) {
    float e1v = __expf(sw1[l] - m1);
    float e2v = __expf(sw2[l] - m2);
    sw1[l] = e1v; sw2[l] = e2v;
    d1p += e1v; d2p += e2v;
  }
  __syncthreads();
  float inv1 = 1.f / block_reduce(d1p, false, redbuf);
  float inv2 = 1.f / block_reduce(d2p, false, redbuf);

  // all barriers done -- divergent tail is safe
  if (t < 192) {
    if (c == 0) {
      // pair_embeddings = all_output[:, 0, :] (exact fp32 copy)
      *(float4*)(out + (size_t)p * DDIM + t * 4) =
          *(const float4*)(X + (size_t)p * LSEQ * DDIM + t * 4);
    }

    const int nch = (ss + 2) >> 2;      // ceil((ss-1)/4)
    const int lo = 1 + c * nch;
    const int hi = min(ss, lo + nch);

    float A1[4] = {0.f, 0.f, 0.f, 0.f}, A2[4] = {0.f, 0.f, 0.f, 0.f};
    const unsigned short* xb = Xbf + (size_t)o * DDIM + t * 4;
#pragma unroll 4
    for (int l = lo; l < hi; ++l) {
      float wa = sw1[l] * inv1, wb = sw2[l] * inv2;
      uint2 xv = *(const uint2*)(xb + (size_t)(l - 1) * DDIM);
      float x0 = __uint_as_float((xv.x & 0xFFFFu) << 16);
      float x1 = __uint_as_float(xv.x & 0xFFFF0000u);
      float x2 = __uint_as_float((xv.y & 0xFFFFu) << 16);
      float x3 = __uint_as_float(xv.y & 0xFFFF0000u);
      A1[0] += wa * x0; A1[1] += wa * x1; A1[2] += wa * x2; A1[3] += wa * x3;
      A2[0] += wb * x0; A2[1] += wb * x1; A2[2] += wb * x2; A2[3] += wb * x3;
    }
    float* e1 = emb + (size_t)(2 * p) * DDIM + t * 4;
    float* e2 = emb + (size_t)(2 * p + 1) * DDIM + t * 4;
    atomicAdd(&e1[0], A1[0]); atomicAdd(&e1[1], A1[1]);
    atomicAdd(&e1[2], A1[2]); atomicAdd(&e1[3], A1[3]);
    atomicAdd(&e2[0], A2[0]); atomicAdd(&e2[1], A2[1]);
    atomicAdd(&e2[2], A2[2]); atomicAdd(&e2[3], A2[3]);
  }
}

// ---------------- fallback kernels (R3 path) ----------------
__global__ __launch_bounds__(256) void k_w1t(const float* __restrict__ W,
                                             unsigned short* __restrict__ Wt) {
  __shared__ float tile[32][33];
  int bk = blockIdx.x * 32, bn = blockIdx.y * 32;
  int tx = threadIdx.x & 31, ty = threadIdx.x >> 5;
#pragma unroll
  for (int i = 0; i < 32; i += 8)
    tile[ty + i][tx] = W[(size_t)(bk + ty + i) * DDIM + bn + tx];
  __syncthreads();
#pragma unroll
  for (int i = 0; i < 32; i += 8)
    Wt[(size_t)(bn + ty + i) * DDIM + bk + tx] = f2bf(tile[tx][ty + i]);
}

__global__ __launch_bounds__(256) void k_pool(
    const float* __restrict__ X, const float* __restrict__ scores,
    const int* __restrict__ fsep, const int* __restrict__ ssep,
    float* __restrict__ emb, float* __restrict__ out) {
  const int p = blockIdx.x;
  const int c = blockIdx.y;
  const int t = threadIdx.x;
  const int fs = fsep[p], ss = ssep[p];
  __shared__ float sw1[LSEQ], sw2[LSEQ];
  __shared__ float redbuf[4];

  float m1p = -INFINITY, m2p = -INFINITY;
  for (int l = t; l < LSEQ; l += 256) {
    float s = scores[p * LSEQ + l];
    float s1 = (l >= 1 && l < fs) ? s : -INFINITY;
    float s2 = (l > fs && l < ss) ? s : -INFINITY;
    sw1[l] = s1; sw2[l] = s2;
    m1p = fmaxf(m1p, s1); m2p = fmaxf(m2p, s2);
  }
  __syncthreads();
  float m1 = block_reduce(m1p, true, redbuf);
  float m2 = block_reduce(m2p, true, redbuf);
  float d1p = 0.f, d2p = 0.f;
  for (int l = t; l < LSEQ; l += 256) {
    float e1v = __expf(sw1[l] - m1);
    float e2v = __expf(sw2[l] - m2);
    sw1[l] = e1v; sw2[l] = e2v;
    d1p += e1v; d2p += e2v;
  }
  __syncthreads();
  float inv1 = 1.f / block_reduce(d1p, false, redbuf);
  float inv2 = 1.f / block_reduce(d2p, false, redbuf);
  const float* base = X + (size_t)p * LSEQ * DDIM;
  if (c == 0) {
    float* po = out + (size_t)p * DDIM;
    po[t] = base[t]; po[t + 256] = base[t + 256]; po[t + 512] = base[t + 512];
  }
  if (t < 192) {
    float4 A1 = make_float4(0.f, 0.f, 0.f, 0.f);
    float4 A2 = make_float4(0.f, 0.f, 0.f, 0.f);
    for (int l = 1 + c; l < ss; l += 8) {
      float wa = sw1[l] * inv1, wb = sw2[l] * inv2;
      float4 x = *(const float4*)(base + (size_t)l * DDIM + 4 * t);
      A1.x += wa * x.x; A1.y += wa * x.y; A1.z += wa * x.z; A1.w += wa * x.w;
      A2.x += wb * x.x; A2.y += wb * x.y; A2.z += wb * x.z; A2.w += wb * x.w;
    }
    float* e1 = emb + (size_t)(2 * p) * DDIM + 4 * t;
    float* e2 = emb + (size_t)(2 * p + 1) * DDIM + 4 * t;
    atomicAdd(&e1[0], A1.x); atomicAdd(&e1[1], A1.y);
    atomicAdd(&e1[2], A1.z); atomicAdd(&e1[3], A1.w);
    atomicAdd(&e2[0], A2.x); atomicAdd(&e2[1], A2.y);
    atomicAdd(&e2[2], A2.z); atomicAdd(&e2[3], A2.w);
  }
}

// ---------------- kernel: segment softmax + weighted sum ----------------
__global__ __launch_bounds__(256) void k_segout(
    const float* __restrict__ emb, const float* __restrict__ sc,
    float* __restrict__ out2) {
  const int g = blockIdx.x;  // 0..31
  const int z = g >> 3, j = g & 7;
  const int t = threadIdx.x;
  int ee[14];
#pragma unroll
  for (int i = 0; i < 7; ++i) ee[i] = 2 * (z * 56 + j * 7 + i);
#pragma unroll
  for (int i = 0; i < 7; ++i) {
    int j2 = i + (i >= j ? 1 : 0);
    int kk = j - (j > j2 ? 1 : 0);
    ee[7 + i] = 2 * (z * 56 + j2 * 7 + kk) + 1;
  }
  float sv[14];
  float m = -INFINITY;
#pragma unroll
  for (int i = 0; i < 14; ++i) { sv[i] = sc[ee[i]]; m = fmaxf(m, sv[i]); }
  float den = 0.f;
#pragma unroll
  for (int i = 0; i < 14; ++i) { sv[i] = __expf(sv[i] - m); den += sv[i]; }
  float inv = 1.f / den;
  float a0 = 0.f, a1 = 0.f, a2 = 0.f;
#pragma unroll
  for (int i = 0; i < 14; ++i) {
    float wgt = sv[i] * inv;
    const float* er = emb + (size_t)ee[i] * DDIM;
    a0 += wgt * er[t]; a1 += wgt * er[t + 256]; a2 += wgt * er[t + 512];
  }
  out2[(size_t)g * DDIM + t] = a0;
  out2[(size_t)g * DDIM + t + 256] = a1;
  out2[(size_t)g * DDIM + t + 512] = a2;
}

// ---------------- launcher ----------------
extern "C" void kernel_launch(void* const* d_in, const int* in_sizes, int n_in,
                              void* d_out, int out_size, void* d_ws, size_t ws_size,
                              hipStream_t stream) {
  const float* X  = (const float*)d_in[0];
  const int* fs   = (const int*)d_in[1];
  const int* ss   = (const int*)d_in[2];
  const float* W1 = (const float*)d_in[3];
  const float* b1 = (const float*)d_in[4];
  const float* v1 = (const float*)d_in[5];
  const float* W2 = (const float*)d_in[7];
  const float* b2 = (const float*)d_in[8];
  const float* v2 = (const float*)d_in[9];
  float* out = (float*)d_out;

  char* ws = (char*)d_ws;
  // fast-path layout (256-B aligned)
  const size_t XBF_ROWS = (size_t)MAXSLAB * 128 + 128;           // 66,688 rows (128 pad)
  const size_t OFF_OFF  = XBF_ROWS * DDIM * 2;                   // 102,432,768
  const size_t OFF_WT1  = OFF_OFF + 1024;
  const size_t OFF_WT2  = OFF_WT1 + 1179648;
  const size_t OFF_SP   = OFF_WT2 + 1179648;                     // scores_part: 12*66688*4
  const size_t OFF_SC2  = OFF_SP + (size_t)12 * SPROWS * 4;      // sc (zeroed)
  const size_t OFF_EMB  = OFF_SC2 + 2048;                        // emb (zeroed, atomicAdd)
  const size_t ZBYTES   = (size_t)PREP_ZB * 4096;                // 1,380,352 zeroed (sc+emb)
  const size_t NEED     = OFF_SC2 + ZBYTES + 256;                // ~109.4 MB

  if (ws_size >= NEED) {
    unsigned short* Xbf = (unsigned short*)ws;
    int*   off     = (int*)(ws + OFF_OFF);
    unsigned short* Wt1 = (unsigned short*)(ws + OFF_WT1);
    unsigned short* Wt2 = (unsigned short*)(ws + OFF_WT2);
    float* spart    = (float*)(ws + OFF_SP);
    float* sc       = (float*)(ws + OFF_SC2);
    float* emb      = (float*)(ws + OFF_EMB);

    k_prep<<<PREP_SCAN + 1 + PREP_ZB, 256, 0, stream>>>(
        X, W1, W2, Wt1, Wt2, ss, off, (unsigned int*)sc, Xbf);
    k_gemm_c<<<65 * 48, 256, 0, stream>>>(Xbf, Wt1, b1, v1, off, spart);
    k_pool3<<<dim3(NPAIR, 4), 256, 0, stream>>>(Xbf, X, spart, fs, ss, off, emb, out);
    k_gemm_score<<<dim3(6, 4), 256, 0, stream>>>(emb, Wt2, b2, v2, sc, 448, 0);
    k_segout<<<32, 256, 0, stream>>>(emb, sc, out + (size_t)NPAIR * DDIM);
  } else {
    // fallback (R3 path, ~2.9 MB ws)
    unsigned short* Wt = (unsigned short*)ws;
    float* scores = (float*)(ws + 1179648);
    float* emb    = (float*)(ws + 1493248);
    float* sc     = scores;

    k_w1t<<<dim3(24, 24), 256, 0, stream>>>(W1, Wt);
    hipMemsetAsync(scores, 0, MROWS1 * sizeof(float), stream);
    hipMemsetAsync(emb, 0, 448 * DDIM * sizeof(float), stream);
    k_gemm_score<<<77 * 48, 256, 0, stream>>>(X, Wt, b1, v1, scores, MROWS1, 1);
    k_pool<<<dim3(NPAIR, 8), 256, 0, stream>>>(X, scores, fs, ss, emb, out);
    k_w1t<<<dim3(24, 24), 256, 0, stream>>>(W2, Wt);
    hipMemsetAsync(sc, 0, 448 * sizeof(float), stream);
    k_gemm_score<<<dim3(6, 4), 256, 0, stream>>>(emb, Wt, b2, v2, sc, 448, 0);
    k_segout<<<32, 256, 0, stream>>>(emb, sc, out + (size_t)NPAIR * DDIM);
  }
}